// Round 1
// baseline (457.206 us; speedup 1.0000x reference)
//
#include <hip/hip_runtime.h>
#include <hip/hip_bf16.h>

// Shapes (compile-time constants for this problem)
// B=8, S=2048, E=128, H=8, D=16;  BH = B*H = 64;  N = B*S = 16384

typedef __attribute__((ext_vector_type(4))) float f32x4;
typedef __attribute__((ext_vector_type(8))) short bf16x8;
typedef __attribute__((ext_vector_type(8))) _Float16 half8;

static __device__ inline short f2bf(float f) {
  union { float f; unsigned u; } x; x.f = f;
  unsigned r = (x.u + 0x7fffu + ((x.u >> 16) & 1u)) >> 16;
  return (short)r;
}

// ---------------- projection: out = (x @ W^T + b) * scale ----------------
// MODE 0: bf16 out scattered [B,H,S,D] (Q / K)
// MODE 1: bf16 out scattered [B,H,D,S] (V transposed)
// MODE 2: fp32 out [N,E]               (final Wo projection)
template <int MODE>
__global__ __launch_bounds__(256) void proj_kernel(const float* __restrict__ x,
                                                   const float* __restrict__ W,
                                                   const float* __restrict__ bias,
                                                   void* __restrict__ out,
                                                   float scale) {
  __shared__ float Ws[128][129];   // +1 pad: e-indexed reads spread banks
  __shared__ float xs[16][132];    // +4 pad: 4 r-groups per wave spread banks
  const int t = threadIdx.x;
  const int rb = blockIdx.x * 16;
  #pragma unroll
  for (int i = 0; i < 64; ++i) {           // 128*128 / 256
    int idx = t + 256 * i;
    Ws[idx >> 7][idx & 127] = W[idx];
  }
  #pragma unroll
  for (int i = 0; i < 8; ++i) {            // 16*128 / 256
    int idx = t + 256 * i;
    xs[idx >> 7][idx & 127] = x[(size_t)rb * 128 + idx];
  }
  __syncthreads();
  const int r = t >> 4;      // 0..15 row within tile
  const int e0 = t & 15;     // output col base
  float acc[8];
  #pragma unroll
  for (int j = 0; j < 8; ++j) acc[j] = bias[e0 + 16 * j];
  for (int c = 0; c < 128; ++c) {
    float xv = xs[r][c];
    #pragma unroll
    for (int j = 0; j < 8; ++j) acc[j] += xv * Ws[e0 + 16 * j][c];
  }
  const int n = rb + r;
  const int bidx = n >> 11, s = n & 2047;
  if (MODE == 2) {
    float* o = (float*)out;
    #pragma unroll
    for (int j = 0; j < 8; ++j) o[(size_t)n * 128 + e0 + 16 * j] = acc[j] * scale;
  } else {
    __hip_bfloat16* o = (__hip_bfloat16*)out;
    #pragma unroll
    for (int j = 0; j < 8; ++j) {
      int e = e0 + 16 * j, h = e >> 4, d = e & 15;
      size_t idx = (MODE == 0)
          ? ((size_t)(bidx * 8 + h) * 2048 + s) * 16 + d
          : ((size_t)(bidx * 8 + h) * 16 + d) * 2048 + s;
      o[idx] = __float2bfloat16(acc[j] * scale);
    }
  }
}

// ---------------- fused attention ----------------
// grid: 64 heads * 128 q-tiles; block: 256 thr (4 waves); 16 q-rows per block.
// Qg,Kg: [BH][S][16] bf16 (Q pre-scaled by 0.25); Vt: [BH][16][S] bf16.
__global__ __launch_bounds__(256) void attn_kernel(const __hip_bfloat16* __restrict__ Qg,
                                                   const __hip_bfloat16* __restrict__ Kg,
                                                   const __hip_bfloat16* __restrict__ Vt,
                                                   float* __restrict__ attn_out,
                                                   float* __restrict__ ctx_out) {
  __shared__ _Float16 sS[16][2056];   // fp16 raw scores, then exp(s-max); pad 8 halfs
  __shared__ float psum[4][16][16];
  __shared__ float inv_s[16];
  const int t = threadIdx.x;
  const int wv = t >> 6, lane = t & 63;
  const int bh = blockIdx.x >> 7;
  const int q0 = (blockIdx.x & 127) * 16;
  const int col = lane & 15;
  const int g4 = lane >> 4;        // 0..3
  const int dh = g4 & 1;           // d-half for K=32 fragments

  // ---- Phase A: S = (Q*0.25) K^T via mfma 16x16x32 (upper-K half of A zeroed) ----
  bf16x8 afrag = {};
  if (lane < 32)
    afrag = *(const bf16x8*)(Qg + (((size_t)bh * 2048 + q0 + col) * 16 + dh * 8));
  const __hip_bfloat16* kbase = Kg + (size_t)bh * 2048 * 16;
  for (int i = 0; i < 32; ++i) {
    int kt = wv * 32 + i;          // 16-wide k-tile index (0..127)
    bf16x8 bfrag = *(const bf16x8*)(kbase + ((size_t)(kt * 16 + col) * 16 + dh * 8));
    f32x4 c = __builtin_amdgcn_mfma_f32_16x16x32_bf16(afrag, bfrag,
                                                      (f32x4){0.f, 0.f, 0.f, 0.f}, 0, 0, 0);
    #pragma unroll
    for (int r = 0; r < 4; ++r)
      sS[g4 * 4 + r][kt * 16 + col] = (_Float16)c[r];   // C: col=lane&15, row=4*(lane>>4)+r
  }
  __syncthreads();

  // ---- Phase B: row softmax (16 threads per row) ----
  {
    const int q = t >> 4, c16 = t & 15;
    float mx = -1e30f;
    for (int m = 0; m < 16; ++m) {
      half8 v = *(const half8*)&sS[q][c16 * 8 + m * 128];
      #pragma unroll
      for (int j = 0; j < 8; ++j) mx = fmaxf(mx, (float)v[j]);
    }
    #pragma unroll
    for (int off = 8; off; off >>= 1) mx = fmaxf(mx, __shfl_xor(mx, off));
    float sum = 0.f;
    for (int m = 0; m < 16; ++m) {
      half8 v = *(const half8*)&sS[q][c16 * 8 + m * 128];
      half8 o;
      #pragma unroll
      for (int j = 0; j < 8; ++j) {
        float e = __expf((float)v[j] - mx);
        sum += e;
        o[j] = (_Float16)e;
      }
      *(half8*)&sS[q][c16 * 8 + m * 128] = o;
    }
    #pragma unroll
    for (int off = 8; off; off >>= 1) sum += __shfl_xor(sum, off);
    if (c16 == 0) inv_s[q] = 1.f / sum;
  }
  __syncthreads();

  // ---- Phase C: write normalized attention rows (fp32, coalesced f32x4) ----
  {
    float* arow = attn_out + ((size_t)bh * 2048 + q0) * 2048;
    const int k0 = t * 8;
    for (int q = 0; q < 16; ++q) {
      float inv = inv_s[q];
      half8 v = *(const half8*)&sS[q][k0];
      f32x4 w0, w1;
      #pragma unroll
      for (int j = 0; j < 4; ++j) { w0[j] = (float)v[j] * inv; w1[j] = (float)v[j + 4] * inv; }
      *(f32x4*)(arow + (size_t)q * 2048 + k0)     = w0;
      *(f32x4*)(arow + (size_t)q * 2048 + k0 + 4) = w1;
    }
  }

  // ---- Phase D: ctx = P V via mfma 16x16x32 (waves split K, reduce in LDS) ----
  {
    const float inva = inv_s[col];     // A-frag row = col
    const __hip_bfloat16* vbase = Vt + ((size_t)bh * 16 + col) * 2048;  // B-frag col = col
    f32x4 acc = {0.f, 0.f, 0.f, 0.f};
    for (int i = 0; i < 16; ++i) {
      int kb = (wv * 16 + i) * 32;
      half8 pv = *(const half8*)&sS[col][kb + 8 * g4];
      bf16x8 a;
      #pragma unroll
      for (int j = 0; j < 8; ++j) a[j] = f2bf((float)pv[j] * inva);
      bf16x8 b = *(const bf16x8*)(vbase + kb + 8 * g4);
      acc = __builtin_amdgcn_mfma_f32_16x16x32_bf16(a, b, acc, 0, 0, 0);
    }
    #pragma unroll
    for (int r = 0; r < 4; ++r) psum[wv][g4 * 4 + r][col] = acc[r];
  }
  __syncthreads();
  {
    const int q = t >> 4, d = t & 15;
    float s = psum[0][q][d] + psum[1][q][d] + psum[2][q][d] + psum[3][q][d];
    const int b = bh >> 3, h = bh & 7;
    ctx_out[(size_t)(b * 2048 + q0 + q) * 128 + h * 16 + d] = s;
  }
}

extern "C" void kernel_launch(void* const* d_in, const int* in_sizes, int n_in,
                              void* d_out, int out_size, void* d_ws, size_t ws_size,
                              hipStream_t stream) {
  const float* query = (const float*)d_in[0];
  const float* key   = (const float*)d_in[1];
  const float* value = (const float*)d_in[2];
  const float* Wq    = (const float*)d_in[3];
  const float* bq    = (const float*)d_in[4];
  const float* Wk    = (const float*)d_in[5];
  const float* bk    = (const float*)d_in[6];
  const float* Wv    = (const float*)d_in[7];
  const float* bv    = (const float*)d_in[8];
  const float* Wo    = (const float*)d_in[9];
  const float* bo    = (const float*)d_in[10];

  float* out  = (float*)d_out;                          // [B,S,E] = 2,097,152 floats
  float* attn = out + (size_t)8 * 2048 * 128;           // [B,H,S,S]

  // workspace: Q,K bf16 [64][2048][16], V^T bf16 [64][16][2048], ctx fp32 [B,S,E]
  __hip_bfloat16* Qw = (__hip_bfloat16*)d_ws;
  __hip_bfloat16* Kw = Qw + (size_t)64 * 2048 * 16;
  __hip_bfloat16* Vw = Kw + (size_t)64 * 2048 * 16;
  float*          ctx = (float*)(Vw + (size_t)64 * 2048 * 16);

  dim3 blk(256);
  proj_kernel<0><<<1024, blk, 0, stream>>>(query, Wq, bq, Qw, 0.25f);  // 1/sqrt(D) folded into Q
  proj_kernel<0><<<1024, blk, 0, stream>>>(key,   Wk, bk, Kw, 1.0f);
  proj_kernel<1><<<1024, blk, 0, stream>>>(value, Wv, bv, Vw, 1.0f);
  attn_kernel<<<8192, blk, 0, stream>>>(Qw, Kw, Vw, attn, ctx);
  proj_kernel<2><<<1024, blk, 0, stream>>>(ctx, Wo, bo, d_out, 1.0f);
}